// Round 1
// baseline (1175.338 us; speedup 1.0000x reference)
//
#include <hip/hip_runtime.h>

#define D 128
#define NEG_SLOPE 0.01f

typedef float v4f __attribute__((ext_vector_type(4)));
typedef short short8 __attribute__((ext_vector_type(8)));

static __device__ __forceinline__ short f2bf(float f) {
    unsigned u = __float_as_uint(f);
    unsigned r = (u + 0x7fffu + ((u >> 16) & 1u)) >> 16;   // round-nearest-even
    return (short)r;
}

// ---------------- W fp32 -> bf16 conversion (both matrices) ----------------
__global__ __launch_bounds__(256) void wconv_kernel(const float* __restrict__ W1,
                                                    const float* __restrict__ W2,
                                                    short* __restrict__ Wbf) {
    int i = blockIdx.x * 256 + threadIdx.x;   // 0..16383
    if (i < D * D) {
        Wbf[i]         = f2bf(W1[i]);
        Wbf[D * D + i] = f2bf(W2[i]);
    }
}

// ---------------- edge gather-scale + scatter-add ----------------
// 32 threads per edge, float4 per thread (128 dims)
__global__ __launch_bounds__(256) void scatter_kernel(const float* __restrict__ feat,
                                                      const int* __restrict__ tgt,
                                                      const int* __restrict__ nbr,
                                                      const float* __restrict__ vals,
                                                      float* __restrict__ hn, int E) {
    int idx  = blockIdx.x * 256 + threadIdx.x;
    int e    = idx >> 5;
    int lane = idx & 31;
    if (e >= E) return;
    int   nb = nbr[e];
    int   tg = tgt[e];
    float v  = vals[e];
    float4 f = ((const float4*)(feat + (long)nb * D))[lane];
    float* dst = hn + (long)tg * D + lane * 4;
    atomicAdd(dst + 0, f.x * v);
    atomicAdd(dst + 1, f.y * v);
    atomicAdd(dst + 2, f.z * v);
    atomicAdd(dst + 3, f.w * v);
}

// ---------------- fused dual-GEMM + bias + leaky relu ----------------
// one wave: 16 nodes x all 128 outs. K=128 in 4 steps of 32.
__global__ __launch_bounds__(256) void gemm_kernel(const float* __restrict__ feat,
                                                   const float* __restrict__ hn,
                                                   const short* __restrict__ Wbf,
                                                   const float* __restrict__ b1,
                                                   const float* __restrict__ b2,
                                                   float* __restrict__ out, int nNodes) {
    int lane = threadIdx.x & 63;
    int wid  = (blockIdx.x * 256 + threadIdx.x) >> 6;
    int m0   = wid * 16;
    if (m0 >= nNodes) return;

    int mrow = lane & 15;   // A: m index / B: n index / D: col index
    int quad = lane >> 4;   // A/B: k-group / D: row-group

    const float* frow = feat + (long)(m0 + mrow) * D + quad * 8;
    const float* hrow = hn   + (long)(m0 + mrow) * D + quad * 8;

    v4f acc[8];
#pragma unroll
    for (int i = 0; i < 8; i++) acc[i] = (v4f)(0.0f);

#pragma unroll
    for (int s = 0; s < 4; s++) {
        float4 fa = ((const float4*)(frow + s * 32))[0];
        float4 fb = ((const float4*)(frow + s * 32))[1];
        float4 ha = ((const float4*)(hrow + s * 32))[0];
        float4 hb = ((const float4*)(hrow + s * 32))[1];

        short8 a1, a2;
        a1[0] = f2bf(fa.x + ha.x); a2[0] = f2bf(fa.x * ha.x);
        a1[1] = f2bf(fa.y + ha.y); a2[1] = f2bf(fa.y * ha.y);
        a1[2] = f2bf(fa.z + ha.z); a2[2] = f2bf(fa.z * ha.z);
        a1[3] = f2bf(fa.w + ha.w); a2[3] = f2bf(fa.w * ha.w);
        a1[4] = f2bf(fb.x + hb.x); a2[4] = f2bf(fb.x * hb.x);
        a1[5] = f2bf(fb.y + hb.y); a2[5] = f2bf(fb.y * hb.y);
        a1[6] = f2bf(fb.z + hb.z); a2[6] = f2bf(fb.z * hb.z);
        a1[7] = f2bf(fb.w + hb.w); a2[7] = f2bf(fb.w * hb.w);

#pragma unroll
        for (int ot = 0; ot < 8; ot++) {
            short8 bf1 = *(const short8*)(Wbf + ((ot * 16 + mrow) * D) + s * 32 + quad * 8);
            short8 bf2 = *(const short8*)(Wbf + D * D + ((ot * 16 + mrow) * D) + s * 32 + quad * 8);
            acc[ot] = __builtin_amdgcn_mfma_f32_16x16x32_bf16(a1, bf1, acc[ot], 0, 0, 0);
            acc[ot] = __builtin_amdgcn_mfma_f32_16x16x32_bf16(a2, bf2, acc[ot], 0, 0, 0);
        }
    }

#pragma unroll
    for (int ot = 0; ot < 8; ot++) {
        int   o    = ot * 16 + mrow;
        float bias = b1[o] + b2[o];
#pragma unroll
        for (int r = 0; r < 4; r++) {
            int   node = m0 + quad * 4 + r;
            float v    = acc[ot][r] + bias;
            out[(long)node * D + o] = (v >= 0.0f) ? v : NEG_SLOPE * v;
        }
    }
}

extern "C" void kernel_launch(void* const* d_in, const int* in_sizes, int n_in,
                              void* d_out, int out_size, void* d_ws, size_t ws_size,
                              hipStream_t stream) {
    const float* feat = (const float*)d_in[0];
    const int*   tgt  = (const int*)d_in[1];
    const int*   nbr  = (const int*)d_in[2];
    const float* vals = (const float*)d_in[3];
    const float* W1   = (const float*)d_in[4];
    const float* b1   = (const float*)d_in[5];
    const float* W2   = (const float*)d_in[6];
    const float* b2   = (const float*)d_in[7];
    float*       out  = (float*)d_out;

    int E      = in_sizes[1];
    int nNodes = out_size / D;

    float* hn  = (float*)d_ws;
    short* Wbf = (short*)((char*)d_ws + (size_t)nNodes * D * sizeof(float));

    hipMemsetAsync(hn, 0, (size_t)nNodes * D * sizeof(float), stream);
    wconv_kernel<<<(D * D + 255) / 256, 256, 0, stream>>>(W1, W2, Wbf);
    scatter_kernel<<<(E * 32 + 255) / 256, 256, 0, stream>>>(feat, tgt, nbr, vals, hn, E);

    int nWaves  = (nNodes + 15) / 16;
    int nBlocks = (nWaves + 3) / 4;
    gemm_kernel<<<nBlocks, 256, 0, stream>>>(feat, hn, Wbf, b1, b2, out, nNodes);
}

// Round 2
// 273.800 us; speedup vs baseline: 4.2927x; 4.2927x over previous
//
#include <hip/hip_runtime.h>

#define D 128
#define NEG_SLOPE 0.01f

typedef float v4f __attribute__((ext_vector_type(4)));
typedef short short8 __attribute__((ext_vector_type(8)));

static __device__ __forceinline__ short f2bf(float f) {
    unsigned u = __float_as_uint(f);
    unsigned r = (u + 0x7fffu + ((u >> 16) & 1u)) >> 16;   // round-nearest-even
    return (short)r;
}

// ---------------- W fp32 -> bf16 conversion (both matrices) ----------------
__global__ __launch_bounds__(256) void wconv_kernel(const float* __restrict__ W1,
                                                    const float* __restrict__ W2,
                                                    short* __restrict__ Wbf) {
    int i = blockIdx.x * 256 + threadIdx.x;   // 0..16383
    if (i < D * D) {
        Wbf[i]         = f2bf(W1[i]);
        Wbf[D * D + i] = f2bf(W2[i]);
    }
}

// ---------------- CSR build: histogram ----------------
__global__ __launch_bounds__(256) void hist_kernel(const int* __restrict__ tgt,
                                                   int* __restrict__ deg, int E) {
    int e = blockIdx.x * 256 + threadIdx.x;
    if (e < E) atomicAdd(&deg[tgt[e]], 1);
}

// ---------------- scan step A: per-block reduce of deg ----------------
__global__ __launch_bounds__(256) void scanA_kernel(const int* __restrict__ deg,
                                                    int* __restrict__ bsum, int n) {
    __shared__ int tmp[256];
    int i = blockIdx.x * 256 + threadIdx.x;
    tmp[threadIdx.x] = (i < n) ? deg[i] : 0;
    __syncthreads();
    for (int s = 128; s > 0; s >>= 1) {
        if (threadIdx.x < s) tmp[threadIdx.x] += tmp[threadIdx.x + s];
        __syncthreads();
    }
    if (threadIdx.x == 0) bsum[blockIdx.x] = tmp[0];
}

// ---------------- scan step B: single-block exclusive scan of block sums ----
__global__ __launch_bounds__(256) void scanB_kernel(const int* __restrict__ bsum,
                                                    int* __restrict__ boff, int nb) {
    __shared__ int tmp[256];
    int v = (threadIdx.x < nb) ? bsum[threadIdx.x] : 0;
    tmp[threadIdx.x] = v;
    __syncthreads();
    for (int d = 1; d < 256; d <<= 1) {
        int t = (threadIdx.x >= d) ? tmp[threadIdx.x - d] : 0;
        __syncthreads();
        tmp[threadIdx.x] += t;
        __syncthreads();
    }
    if (threadIdx.x < nb) boff[threadIdx.x] = tmp[threadIdx.x] - v;  // exclusive
}

// ---------------- scan step C: per-block exclusive scan + offset ----------
__global__ __launch_bounds__(256) void scanC_kernel(const int* __restrict__ deg,
                                                    const int* __restrict__ boff,
                                                    int* __restrict__ offs, int n) {
    __shared__ int tmp[256];
    int i = blockIdx.x * 256 + threadIdx.x;
    int v = (i < n) ? deg[i] : 0;
    tmp[threadIdx.x] = v;
    __syncthreads();
    for (int d = 1; d < 256; d <<= 1) {
        int t = (threadIdx.x >= d) ? tmp[threadIdx.x - d] : 0;
        __syncthreads();
        tmp[threadIdx.x] += t;
        __syncthreads();
    }
    if (i < n) offs[i] = tmp[threadIdx.x] - v + boff[blockIdx.x];
}

// ---------------- CSR fill: packed (neighbor, value) per edge -------------
__global__ __launch_bounds__(256) void fill_kernel(const int* __restrict__ tgt,
                                                   const int* __restrict__ nbr,
                                                   const float* __restrict__ vals,
                                                   const int* __restrict__ offs,
                                                   int* __restrict__ cursor,
                                                   int2* __restrict__ edata, int E) {
    int e = blockIdx.x * 256 + threadIdx.x;
    if (e >= E) return;
    int t    = tgt[e];
    int slot = atomicAdd(&cursor[t], 1);
    int2 ed;
    ed.x = nbr[e];
    ed.y = __float_as_int(vals[e]);
    edata[offs[t] + slot] = ed;
}

// ---------------- gather: one wave per node, zero fp atomics --------------
__global__ __launch_bounds__(256) void gather_kernel(const float* __restrict__ feat,
                                                     const int2* __restrict__ edata,
                                                     const int* __restrict__ offs,
                                                     const int* __restrict__ deg,
                                                     float* __restrict__ hn, int nNodes) {
    int wid  = (blockIdx.x * 256 + threadIdx.x) >> 6;
    int lane = threadIdx.x & 63;
    if (wid >= nNodes) return;
    int start = offs[wid];
    int d     = deg[wid];
    float2 acc = {0.0f, 0.0f};
    for (int j = 0; j < d; j++) {
        int2  ed = edata[start + j];
        float v  = __int_as_float(ed.y);
        float2 f = ((const float2*)(feat + (long)ed.x * D))[lane];
        acc.x += f.x * v;
        acc.y += f.y * v;
    }
    ((float2*)(hn + (long)wid * D))[lane] = acc;
}

// ---------------- fused dual-GEMM + bias + leaky relu ----------------
// one wave: 16 nodes x all 128 outs. K=128 in 4 steps of 32.
__global__ __launch_bounds__(256) void gemm_kernel(const float* __restrict__ feat,
                                                   const float* __restrict__ hn,
                                                   const short* __restrict__ Wbf,
                                                   const float* __restrict__ b1,
                                                   const float* __restrict__ b2,
                                                   float* __restrict__ out, int nNodes) {
    int lane = threadIdx.x & 63;
    int wid  = (blockIdx.x * 256 + threadIdx.x) >> 6;
    int m0   = wid * 16;
    if (m0 >= nNodes) return;

    int mrow = lane & 15;   // A: m index / B: n index / D: col index
    int quad = lane >> 4;   // A/B: k-group / D: row-group

    const float* frow = feat + (long)(m0 + mrow) * D + quad * 8;
    const float* hrow = hn   + (long)(m0 + mrow) * D + quad * 8;

    v4f acc[8];
#pragma unroll
    for (int i = 0; i < 8; i++) acc[i] = (v4f)(0.0f);

#pragma unroll
    for (int s = 0; s < 4; s++) {
        float4 fa = ((const float4*)(frow + s * 32))[0];
        float4 fb = ((const float4*)(frow + s * 32))[1];
        float4 ha = ((const float4*)(hrow + s * 32))[0];
        float4 hb = ((const float4*)(hrow + s * 32))[1];

        short8 a1, a2;
        a1[0] = f2bf(fa.x + ha.x); a2[0] = f2bf(fa.x * ha.x);
        a1[1] = f2bf(fa.y + ha.y); a2[1] = f2bf(fa.y * ha.y);
        a1[2] = f2bf(fa.z + ha.z); a2[2] = f2bf(fa.z * ha.z);
        a1[3] = f2bf(fa.w + ha.w); a2[3] = f2bf(fa.w * ha.w);
        a1[4] = f2bf(fb.x + hb.x); a2[4] = f2bf(fb.x * hb.x);
        a1[5] = f2bf(fb.y + hb.y); a2[5] = f2bf(fb.y * hb.y);
        a1[6] = f2bf(fb.z + hb.z); a2[6] = f2bf(fb.z * hb.z);
        a1[7] = f2bf(fb.w + hb.w); a2[7] = f2bf(fb.w * hb.w);

#pragma unroll
        for (int ot = 0; ot < 8; ot++) {
            short8 bf1 = *(const short8*)(Wbf + ((ot * 16 + mrow) * D) + s * 32 + quad * 8);
            short8 bf2 = *(const short8*)(Wbf + D * D + ((ot * 16 + mrow) * D) + s * 32 + quad * 8);
            acc[ot] = __builtin_amdgcn_mfma_f32_16x16x32_bf16(a1, bf1, acc[ot], 0, 0, 0);
            acc[ot] = __builtin_amdgcn_mfma_f32_16x16x32_bf16(a2, bf2, acc[ot], 0, 0, 0);
        }
    }

#pragma unroll
    for (int ot = 0; ot < 8; ot++) {
        int   o    = ot * 16 + mrow;
        float bias = b1[o] + b2[o];
#pragma unroll
        for (int r = 0; r < 4; r++) {
            int   node = m0 + quad * 4 + r;
            float v    = acc[ot][r] + bias;
            out[(long)node * D + o] = (v >= 0.0f) ? v : NEG_SLOPE * v;
        }
    }
}

extern "C" void kernel_launch(void* const* d_in, const int* in_sizes, int n_in,
                              void* d_out, int out_size, void* d_ws, size_t ws_size,
                              hipStream_t stream) {
    const float* feat = (const float*)d_in[0];
    const int*   tgt  = (const int*)d_in[1];
    const int*   nbr  = (const int*)d_in[2];
    const float* vals = (const float*)d_in[3];
    const float* W1   = (const float*)d_in[4];
    const float* b1   = (const float*)d_in[5];
    const float* W2   = (const float*)d_in[6];
    const float* b2   = (const float*)d_in[7];
    float*       out  = (float*)d_out;

    int E      = in_sizes[1];
    int nNodes = out_size / D;

    // ---- workspace layout ----
    int*  deg    = (int*)d_ws;                 // N
    int*  cursor = deg + nNodes;               // N
    int*  offs   = cursor + nNodes;            // N
    int*  bsum   = offs + nNodes;              // 256
    int*  boff   = bsum + 256;                 // 256
    int2* edata  = (int2*)(boff + 256);        // E   (8B-aligned: 3N+512 ints)
    short* Wbf   = (short*)(edata + E);        // 2*D*D
    float* hn    = (float*)(Wbf + 2 * D * D);  // N*D

    int nbA = (nNodes + 255) / 256;            // 196 blocks for N=50000
    int nbE = (E + 255) / 256;

    hipMemsetAsync(deg, 0, (size_t)2 * nNodes * sizeof(int), stream);  // deg + cursor
    wconv_kernel<<<(D * D + 255) / 256, 256, 0, stream>>>(W1, W2, Wbf);
    hist_kernel<<<nbE, 256, 0, stream>>>(tgt, deg, E);
    scanA_kernel<<<nbA, 256, 0, stream>>>(deg, bsum, nNodes);
    scanB_kernel<<<1, 256, 0, stream>>>(bsum, boff, nbA);
    scanC_kernel<<<nbA, 256, 0, stream>>>(deg, boff, offs, nNodes);
    fill_kernel<<<nbE, 256, 0, stream>>>(tgt, nbr, vals, offs, cursor, edata, E);
    gather_kernel<<<(nNodes * 64 + 255) / 256, 256, 0, stream>>>(feat, edata, offs, deg, hn, nNodes);

    int nWaves  = (nNodes + 15) / 16;
    int nBlocks = (nWaves + 3) / 4;
    gemm_kernel<<<nBlocks, 256, 0, stream>>>(feat, hn, Wbf, b1, b2, out, nNodes);
}

// Round 3
// 207.661 us; speedup vs baseline: 5.6599x; 1.3185x over previous
//
#include <hip/hip_runtime.h>

#define D 128
#define CAP 32
#define NEG_SLOPE 0.01f

typedef float v4f __attribute__((ext_vector_type(4)));
typedef short short8 __attribute__((ext_vector_type(8)));

static __device__ __forceinline__ short f2bf(float f) {
    unsigned u = __float_as_uint(f);
    unsigned r = (u + 0x7fffu + ((u >> 16) & 1u)) >> 16;   // round-nearest-even
    return (short)r;
}

// -------- fp32 -> bf16 conversion: features (packed pairs) + both W --------
__global__ __launch_bounds__(256) void conv_kernel(const float* __restrict__ feat,
                                                   const float* __restrict__ W1,
                                                   const float* __restrict__ W2,
                                                   unsigned* __restrict__ featbf,
                                                   short* __restrict__ Wbf, int nPairs) {
    int i = blockIdx.x * 256 + threadIdx.x;
    if (i < nPairs) {
        float2 f = ((const float2*)feat)[i];
        unsigned lo = (unsigned short)f2bf(f.x);
        unsigned hi = (unsigned short)f2bf(f.y);
        featbf[i] = lo | (hi << 16);
    }
    if (i < D * D) {
        Wbf[i]         = f2bf(W1[i]);
        Wbf[D * D + i] = f2bf(W2[i]);
    }
}

// -------- bucket fill: hist + CSR fill in one pass (fixed capacity) --------
__global__ __launch_bounds__(256) void bucket_kernel(const int* __restrict__ tgt,
                                                     const int* __restrict__ nbr,
                                                     const float* __restrict__ vals,
                                                     int* __restrict__ deg,
                                                     int2* __restrict__ edata,
                                                     int* __restrict__ ovf,
                                                     int* __restrict__ ovf_cnt, int E) {
    int e = blockIdx.x * 256 + threadIdx.x;
    if (e >= E) return;
    int t    = tgt[e];
    int slot = atomicAdd(&deg[t], 1);
    if (slot < CAP) {
        int2 ed;
        ed.x = nbr[e];
        ed.y = __float_as_int(vals[e]);
        edata[(long)t * CAP + slot] = ed;
    } else {
        int o  = atomicAdd(ovf_cnt, 1);
        ovf[o] = e;
    }
}

// -------- gather: one wave per node, bf16 feature rows, unroll x4 ----------
__global__ __launch_bounds__(256) void gather_kernel(const unsigned* __restrict__ featbf,
                                                     const int2* __restrict__ edata,
                                                     const int* __restrict__ deg,
                                                     float* __restrict__ hn, int nNodes) {
    int wid  = (blockIdx.x * 256 + threadIdx.x) >> 6;
    int lane = threadIdx.x & 63;
    if (wid >= nNodes) return;
    int d = deg[wid];
    d = d < CAP ? d : CAP;
    const int2* ep = edata + (long)wid * CAP;
    float accx = 0.f, accy = 0.f;
    int j = 0;
    for (; j + 4 <= d; j += 4) {
        int2 e0 = ep[j + 0], e1 = ep[j + 1], e2 = ep[j + 2], e3 = ep[j + 3];
        unsigned u0 = featbf[(long)e0.x * (D / 2) + lane];
        unsigned u1 = featbf[(long)e1.x * (D / 2) + lane];
        unsigned u2 = featbf[(long)e2.x * (D / 2) + lane];
        unsigned u3 = featbf[(long)e3.x * (D / 2) + lane];
        float v0 = __int_as_float(e0.y), v1 = __int_as_float(e1.y);
        float v2 = __int_as_float(e2.y), v3 = __int_as_float(e3.y);
        accx += __uint_as_float(u0 << 16) * v0; accy += __uint_as_float(u0 & 0xffff0000u) * v0;
        accx += __uint_as_float(u1 << 16) * v1; accy += __uint_as_float(u1 & 0xffff0000u) * v1;
        accx += __uint_as_float(u2 << 16) * v2; accy += __uint_as_float(u2 & 0xffff0000u) * v2;
        accx += __uint_as_float(u3 << 16) * v3; accy += __uint_as_float(u3 & 0xffff0000u) * v3;
    }
    for (; j < d; j++) {
        int2 e0 = ep[j];
        unsigned u0 = featbf[(long)e0.x * (D / 2) + lane];
        float v0 = __int_as_float(e0.y);
        accx += __uint_as_float(u0 << 16) * v0;
        accy += __uint_as_float(u0 & 0xffff0000u) * v0;
    }
    float2 o;
    o.x = accx;
    o.y = accy;
    ((float2*)(hn + (long)wid * D))[lane] = o;
}

// -------- overflow fixup (normally 0 edges): fp32 atomics into hn ----------
__global__ __launch_bounds__(256) void ovf_kernel(const int* __restrict__ ovf,
                                                  const int* __restrict__ ovf_cnt,
                                                  const int* __restrict__ tgt,
                                                  const int* __restrict__ nbr,
                                                  const float* __restrict__ vals,
                                                  const float* __restrict__ feat,
                                                  float* __restrict__ hn) {
    int n     = *ovf_cnt;
    int total = n * 32;
    for (int u = blockIdx.x * 256 + threadIdx.x; u < total; u += gridDim.x * 256) {
        int   e    = ovf[u >> 5];
        int   lane = u & 31;
        int   t    = tgt[e];
        int   nb   = nbr[e];
        float v    = vals[e];
        float4 f   = ((const float4*)(feat + (long)nb * D))[lane];
        float* dst = hn + (long)t * D + lane * 4;
        atomicAdd(dst + 0, f.x * v);
        atomicAdd(dst + 1, f.y * v);
        atomicAdd(dst + 2, f.z * v);
        atomicAdd(dst + 3, f.w * v);
    }
}

// ---------------- fused dual-GEMM + bias + leaky relu ----------------
// one wave: 16 nodes x all 128 outs. K=128 in 4 steps of 32.
__global__ __launch_bounds__(256) void gemm_kernel(const float* __restrict__ feat,
                                                   const float* __restrict__ hn,
                                                   const short* __restrict__ Wbf,
                                                   const float* __restrict__ b1,
                                                   const float* __restrict__ b2,
                                                   float* __restrict__ out, int nNodes) {
    int lane = threadIdx.x & 63;
    int wid  = (blockIdx.x * 256 + threadIdx.x) >> 6;
    int m0   = wid * 16;
    if (m0 >= nNodes) return;

    int mrow = lane & 15;   // A: m index / B: n index / D: col index
    int quad = lane >> 4;   // A/B: k-group / D: row-group

    const float* frow = feat + (long)(m0 + mrow) * D + quad * 8;
    const float* hrow = hn   + (long)(m0 + mrow) * D + quad * 8;

    v4f acc[8];
#pragma unroll
    for (int i = 0; i < 8; i++) acc[i] = (v4f)(0.0f);

#pragma unroll
    for (int s = 0; s < 4; s++) {
        float4 fa = ((const float4*)(frow + s * 32))[0];
        float4 fb = ((const float4*)(frow + s * 32))[1];
        float4 ha = ((const float4*)(hrow + s * 32))[0];
        float4 hb = ((const float4*)(hrow + s * 32))[1];

        short8 a1, a2;
        a1[0] = f2bf(fa.x + ha.x); a2[0] = f2bf(fa.x * ha.x);
        a1[1] = f2bf(fa.y + ha.y); a2[1] = f2bf(fa.y * ha.y);
        a1[2] = f2bf(fa.z + ha.z); a2[2] = f2bf(fa.z * ha.z);
        a1[3] = f2bf(fa.w + ha.w); a2[3] = f2bf(fa.w * ha.w);
        a1[4] = f2bf(fb.x + hb.x); a2[4] = f2bf(fb.x * hb.x);
        a1[5] = f2bf(fb.y + hb.y); a2[5] = f2bf(fb.y * hb.y);
        a1[6] = f2bf(fb.z + hb.z); a2[6] = f2bf(fb.z * hb.z);
        a1[7] = f2bf(fb.w + hb.w); a2[7] = f2bf(fb.w * hb.w);

#pragma unroll
        for (int ot = 0; ot < 8; ot++) {
            short8 bf1 = *(const short8*)(Wbf + ((ot * 16 + mrow) * D) + s * 32 + quad * 8);
            short8 bf2 = *(const short8*)(Wbf + D * D + ((ot * 16 + mrow) * D) + s * 32 + quad * 8);
            acc[ot] = __builtin_amdgcn_mfma_f32_16x16x32_bf16(a1, bf1, acc[ot], 0, 0, 0);
            acc[ot] = __builtin_amdgcn_mfma_f32_16x16x32_bf16(a2, bf2, acc[ot], 0, 0, 0);
        }
    }

#pragma unroll
    for (int ot = 0; ot < 8; ot++) {
        int   o    = ot * 16 + mrow;
        float bias = b1[o] + b2[o];
#pragma unroll
        for (int r = 0; r < 4; r++) {
            int   node = m0 + quad * 4 + r;
            float v    = acc[ot][r] + bias;
            out[(long)node * D + o] = (v >= 0.0f) ? v : NEG_SLOPE * v;
        }
    }
}

extern "C" void kernel_launch(void* const* d_in, const int* in_sizes, int n_in,
                              void* d_out, int out_size, void* d_ws, size_t ws_size,
                              hipStream_t stream) {
    const float* feat = (const float*)d_in[0];
    const int*   tgt  = (const int*)d_in[1];
    const int*   nbr  = (const int*)d_in[2];
    const float* vals = (const float*)d_in[3];
    const float* W1   = (const float*)d_in[4];
    const float* b1   = (const float*)d_in[5];
    const float* W2   = (const float*)d_in[6];
    const float* b2   = (const float*)d_in[7];
    float*       out  = (float*)d_out;

    int E      = in_sizes[1];
    int nNodes = out_size / D;

    // ---- workspace layout ----
    int*      deg     = (int*)d_ws;                    // N
    int*      ovf_cnt = deg + nNodes;                  // 1 (+1 pad)
    int*      ovf     = ovf_cnt + 2;                   // E
    int2*     edata   = (int2*)(ovf + E);              // N*CAP (8B aligned: N+2+E even)
    short*    Wbf     = (short*)(edata + (long)nNodes * CAP);  // 2*D*D
    unsigned* featbf  = (unsigned*)(Wbf + 2 * D * D);  // N*D/2
    float*    hn      = (float*)(featbf + (long)nNodes * (D / 2));  // N*D

    int nPairs = nNodes * (D / 2);   // feature float2 pairs

    hipMemsetAsync(deg, 0, (size_t)(nNodes + 2) * sizeof(int), stream);  // deg + ovf_cnt
    conv_kernel<<<(nPairs + 255) / 256, 256, 0, stream>>>(feat, W1, W2, featbf, Wbf, nPairs);
    bucket_kernel<<<(E + 255) / 256, 256, 0, stream>>>(tgt, nbr, vals, deg, edata, ovf, ovf_cnt, E);
    gather_kernel<<<(nNodes * 64 + 255) / 256, 256, 0, stream>>>(featbf, edata, deg, hn, nNodes);
    ovf_kernel<<<32, 256, 0, stream>>>(ovf, ovf_cnt, tgt, nbr, vals, feat, hn);

    int nWaves  = (nNodes + 15) / 16;
    int nBlocks = (nWaves + 3) / 4;
    gemm_kernel<<<nBlocks, 256, 0, stream>>>(feat, hn, Wbf, b1, b2, out, nNodes);
}

// Round 4
// 182.895 us; speedup vs baseline: 6.4263x; 1.1354x over previous
//
#include <hip/hip_runtime.h>

#define D 128
#define CAP 40
#define NEG_SLOPE 0.01f

typedef float v4f __attribute__((ext_vector_type(4)));
typedef short short8 __attribute__((ext_vector_type(8)));

static __device__ __forceinline__ short f2bf(float f) {
    unsigned u = __float_as_uint(f);
    unsigned r = (u + 0x7fffu + ((u >> 16) & 1u)) >> 16;   // round-nearest-even
    return (short)r;
}
static __device__ __forceinline__ float bflo(unsigned u) { return __uint_as_float(u << 16); }
static __device__ __forceinline__ float bfhi(unsigned u) { return __uint_as_float(u & 0xffff0000u); }
static __device__ __forceinline__ unsigned packbf(float x, float y) {
    return (unsigned)(unsigned short)f2bf(x) | ((unsigned)(unsigned short)f2bf(y) << 16);
}

// -------- fp32 -> bf16 conversion: features (packed pairs) + both W --------
__global__ __launch_bounds__(256) void conv_kernel(const float* __restrict__ feat,
                                                   const float* __restrict__ W1,
                                                   const float* __restrict__ W2,
                                                   unsigned* __restrict__ featbf,
                                                   short* __restrict__ Wbf, int nPairs) {
    int i = blockIdx.x * 256 + threadIdx.x;
    if (i < nPairs) {
        float2 f = ((const float2*)feat)[i];
        featbf[i] = packbf(f.x, f.y);
    }
    if (i < D * D) {
        Wbf[i]         = f2bf(W1[i]);
        Wbf[D * D + i] = f2bf(W2[i]);
    }
}

// -------- bucket fill: hist + CSR fill in one pass (fixed capacity) --------
__global__ __launch_bounds__(256) void bucket_kernel(const int* __restrict__ tgt,
                                                     const int* __restrict__ nbr,
                                                     const float* __restrict__ vals,
                                                     int* __restrict__ deg,
                                                     int2* __restrict__ edata, int E) {
    int e = blockIdx.x * 256 + threadIdx.x;
    if (e >= E) return;
    int t    = tgt[e];
    int slot = atomicAdd(&deg[t], 1);
    if (slot < CAP) {
        int2 ed;
        ed.x = nbr[e];
        ed.y = __float_as_int(vals[e]);
        edata[(long)t * CAP + slot] = ed;
    }
    // slot >= CAP: node handled exactly by gather's full-scan fallback
}

// -------- gather + x1/x2 epilogue: one wave per node, zero fp atomics ------
// writes X1 = bf16(f + h), X2 = bf16(f * h) packed pairs
__global__ __launch_bounds__(256) void gather_kernel(const unsigned* __restrict__ featbf,
                                                     const int2* __restrict__ edata,
                                                     const int* __restrict__ deg,
                                                     const int* __restrict__ tgt,
                                                     const int* __restrict__ nbr,
                                                     const float* __restrict__ vals,
                                                     unsigned* __restrict__ X1,
                                                     unsigned* __restrict__ X2,
                                                     int nNodes, int E) {
    int wid  = (blockIdx.x * 256 + threadIdx.x) >> 6;
    int lane = threadIdx.x & 63;
    if (wid >= nNodes) return;
    int d = deg[wid];
    float accx = 0.f, accy = 0.f;

    if (d <= CAP) {
        const int2* ep = edata + (long)wid * CAP;
        int j = 0;
        for (; j + 4 <= d; j += 4) {
            int2 e0 = ep[j + 0], e1 = ep[j + 1], e2 = ep[j + 2], e3 = ep[j + 3];
            unsigned u0 = featbf[(long)e0.x * (D / 2) + lane];
            unsigned u1 = featbf[(long)e1.x * (D / 2) + lane];
            unsigned u2 = featbf[(long)e2.x * (D / 2) + lane];
            unsigned u3 = featbf[(long)e3.x * (D / 2) + lane];
            float v0 = __int_as_float(e0.y), v1 = __int_as_float(e1.y);
            float v2 = __int_as_float(e2.y), v3 = __int_as_float(e3.y);
            accx += bflo(u0) * v0; accy += bfhi(u0) * v0;
            accx += bflo(u1) * v1; accy += bfhi(u1) * v1;
            accx += bflo(u2) * v2; accy += bfhi(u2) * v2;
            accx += bflo(u3) * v3; accy += bfhi(u3) * v3;
        }
        for (; j < d; j++) {
            int2 e0 = ep[j];
            unsigned u0 = featbf[(long)e0.x * (D / 2) + lane];
            float v0 = __int_as_float(e0.y);
            accx += bflo(u0) * v0;
            accy += bfhi(u0) * v0;
        }
    } else {
        // exact fallback (statistically never taken): scan all edges
        for (int base = 0; base < E; base += 64) {
            int e = base + lane;
            int t = (e < E) ? tgt[e] : -1;
            unsigned long long m = __ballot(t == wid);
            while (m) {
                int b = __ffsll((long long)m) - 1;
                m &= m - 1;
                int   ee = base + b;
                int   nb = nbr[ee];
                float v  = vals[ee];
                unsigned u = featbf[(long)nb * (D / 2) + lane];
                accx += bflo(u) * v;
                accy += bfhi(u) * v;
            }
        }
    }

    unsigned uf = featbf[(long)wid * (D / 2) + lane];
    float fx = bflo(uf), fy = bfhi(uf);
    X1[(long)wid * (D / 2) + lane] = packbf(fx + accx, fy + accy);
    X2[(long)wid * (D / 2) + lane] = packbf(fx * accx, fy * accy);
}

// -------- fused dual-GEMM + bias + leaky relu --------
// W staged in LDS (XOR-swizzled); one wave: 32 nodes x all 128 outs.
__global__ __launch_bounds__(256) void gemm_kernel(const short* __restrict__ X1s,
                                                   const short* __restrict__ X2s,
                                                   const short* __restrict__ Wbf,
                                                   const float* __restrict__ b1,
                                                   const float* __restrict__ b2,
                                                   float* __restrict__ out, int nNodes) {
    __shared__ __align__(16) short sW[2 * D * D];   // 64 KB

    int tid = threadIdx.x;
    // stage W: 4096 16-B chunks, XOR-swizzle chunk pos within row by row&15
    for (int c = tid; c < 4096; c += 256) {
        int r  = c >> 4;          // global row 0..255 (mat*128+row)
        int cc = c & 15;          // chunk within row
        int pp = cc ^ (r & 15);
        *(short8*)(&sW[r * D + pp * 8]) = *(const short8*)(Wbf + c * 8);
    }
    __syncthreads();

    int lane = tid & 63;
    int wid  = (blockIdx.x * 256 + tid) >> 6;
    int m0   = wid * 32;
    if (m0 >= nNodes) return;
    bool t2 = (m0 + 16) < nNodes;   // tiles are all-or-nothing (N % 16 == 0)

    int mrow = lane & 15;   // A: m index / B: n index / D: col index
    int quad = lane >> 4;   // A/B: k-group / D: row-group

    const short* xa1 = X1s + (long)(m0 + mrow) * D + quad * 8;        // tile 0
    const short* xa2 = X2s + (long)(m0 + mrow) * D + quad * 8;
    const short* xb1 = xa1 + 16 * D;                                  // tile 1
    const short* xb2 = xa2 + 16 * D;

    v4f acc[2][8];
#pragma unroll
    for (int t = 0; t < 2; t++)
#pragma unroll
        for (int i = 0; i < 8; i++) acc[t][i] = (v4f)(0.0f);

#pragma unroll
    for (int s = 0; s < 4; s++) {
        short8 a1 = *(const short8*)(xa1 + s * 32);
        short8 a2 = *(const short8*)(xa2 + s * 32);
        short8 c1, c2;
        if (t2) {
            c1 = *(const short8*)(xb1 + s * 32);
            c2 = *(const short8*)(xb2 + s * 32);
        }
        int pp = (s * 4 + quad) ^ mrow;   // swizzled chunk
#pragma unroll
        for (int ot = 0; ot < 8; ot++) {
            int row = ot * 16 + mrow;
            short8 w1 = *(const short8*)(&sW[row * D + pp * 8]);
            short8 w2 = *(const short8*)(&sW[D * D + row * D + pp * 8]);
            acc[0][ot] = __builtin_amdgcn_mfma_f32_16x16x32_bf16(a1, w1, acc[0][ot], 0, 0, 0);
            acc[0][ot] = __builtin_amdgcn_mfma_f32_16x16x32_bf16(a2, w2, acc[0][ot], 0, 0, 0);
            if (t2) {
                acc[1][ot] = __builtin_amdgcn_mfma_f32_16x16x32_bf16(c1, w1, acc[1][ot], 0, 0, 0);
                acc[1][ot] = __builtin_amdgcn_mfma_f32_16x16x32_bf16(c2, w2, acc[1][ot], 0, 0, 0);
            }
        }
    }

#pragma unroll
    for (int ot = 0; ot < 8; ot++) {
        int   o    = ot * 16 + mrow;
        float bias = b1[o] + b2[o];
#pragma unroll
        for (int r = 0; r < 4; r++) {
            int   node = m0 + quad * 4 + r;
            float v    = acc[0][ot][r] + bias;
            out[(long)node * D + o] = (v >= 0.0f) ? v : NEG_SLOPE * v;
            if (t2) {
                float w = acc[1][ot][r] + bias;
                out[(long)(node + 16) * D + o] = (w >= 0.0f) ? w : NEG_SLOPE * w;
            }
        }
    }
}

extern "C" void kernel_launch(void* const* d_in, const int* in_sizes, int n_in,
                              void* d_out, int out_size, void* d_ws, size_t ws_size,
                              hipStream_t stream) {
    const float* feat = (const float*)d_in[0];
    const int*   tgt  = (const int*)d_in[1];
    const int*   nbr  = (const int*)d_in[2];
    const float* vals = (const float*)d_in[3];
    const float* W1   = (const float*)d_in[4];
    const float* b1   = (const float*)d_in[5];
    const float* W2   = (const float*)d_in[6];
    const float* b2   = (const float*)d_in[7];
    float*       out  = (float*)d_out;

    int E      = in_sizes[1];
    int nNodes = out_size / D;

    // ---- workspace layout ----
    int*      deg    = (int*)d_ws;                              // N (even)
    int2*     edata  = (int2*)(deg + nNodes);                   // N*CAP
    short*    Wbf    = (short*)(edata + (long)nNodes * CAP);    // 2*D*D
    unsigned* featbf = (unsigned*)(Wbf + 2 * D * D);            // N*D/2
    unsigned* X1     = featbf + (long)nNodes * (D / 2);         // N*D/2
    unsigned* X2     = X1 + (long)nNodes * (D / 2);             // N*D/2

    int nPairs = nNodes * (D / 2);

    hipMemsetAsync(deg, 0, (size_t)nNodes * sizeof(int), stream);
    conv_kernel<<<(nPairs + 255) / 256, 256, 0, stream>>>(feat, W1, W2, featbf, Wbf, nPairs);
    bucket_kernel<<<(E + 255) / 256, 256, 0, stream>>>(tgt, nbr, vals, deg, edata, E);
    gather_kernel<<<(nNodes * 64 + 255) / 256, 256, 0, stream>>>(featbf, edata, deg, tgt, nbr, vals,
                                                                 X1, X2, nNodes, E);

    int nPairTiles = (nNodes + 31) / 32;
    int nBlocks    = (nPairTiles + 3) / 4;
    gemm_kernel<<<nBlocks, 256, 0, stream>>>((const short*)X1, (const short*)X2, Wbf, b1, b2, out, nNodes);
}

// Round 5
// 175.397 us; speedup vs baseline: 6.7010x; 1.0427x over previous
//
#include <hip/hip_runtime.h>

#define D 128
#define CAP 40
#define NEG_SLOPE 0.01f

typedef float v4f __attribute__((ext_vector_type(4)));
typedef short short8 __attribute__((ext_vector_type(8)));

static __device__ __forceinline__ short f2bf(float f) {
    unsigned u = __float_as_uint(f);
    unsigned r = (u + 0x7fffu + ((u >> 16) & 1u)) >> 16;   // round-nearest-even
    return (short)r;
}
static __device__ __forceinline__ float bflo(unsigned u) { return __uint_as_float(u << 16); }
static __device__ __forceinline__ float bfhi(unsigned u) { return __uint_as_float(u & 0xffff0000u); }
static __device__ __forceinline__ unsigned packbf(float x, float y) {
    return (unsigned)(unsigned short)f2bf(x) | ((unsigned)(unsigned short)f2bf(y) << 16);
}

// -------- fp32 -> bf16 conversion: features + both W; also zeros deg --------
__global__ __launch_bounds__(256) void conv_kernel(const float* __restrict__ feat,
                                                   const float* __restrict__ W1,
                                                   const float* __restrict__ W2,
                                                   unsigned* __restrict__ featbf,
                                                   short* __restrict__ Wbf,
                                                   int* __restrict__ deg,
                                                   int nPairs, int nNodes) {
    int i = blockIdx.x * 256 + threadIdx.x;
    if (i < nPairs) {
        float2 f = ((const float2*)feat)[i];
        featbf[i] = packbf(f.x, f.y);
    }
    if (i < D * D) {
        Wbf[i]         = f2bf(W1[i]);
        Wbf[D * D + i] = f2bf(W2[i]);
    }
    if (i < nNodes) deg[i] = 0;
}

// -------- bucket fill: hist + CSR fill in one pass (fixed capacity) --------
__global__ __launch_bounds__(256) void bucket_kernel(const int* __restrict__ tgt,
                                                     const int* __restrict__ nbr,
                                                     const float* __restrict__ vals,
                                                     int* __restrict__ deg,
                                                     int2* __restrict__ edata, int E) {
    int e = blockIdx.x * 256 + threadIdx.x;
    if (e >= E) return;
    int t    = tgt[e];
    int slot = atomicAdd(&deg[t], 1);
    if (slot < CAP) {
        int2 ed;
        ed.x = nbr[e];
        ed.y = __float_as_int(vals[e]);
        edata[(long)t * CAP + slot] = ed;
    }
    // slot >= CAP: node handled exactly by gather's full-scan fallback
}

// -------- gather + x1/x2 epilogue: one wave per node, max-MLP --------------
// writes X1 = bf16(f + h), X2 = bf16(f * h) packed pairs
__global__ __launch_bounds__(256) void gather_kernel(const unsigned* __restrict__ featbf,
                                                     const int2* __restrict__ edata,
                                                     const int* __restrict__ deg,
                                                     const int* __restrict__ tgt,
                                                     const int* __restrict__ nbr,
                                                     const float* __restrict__ vals,
                                                     unsigned* __restrict__ X1,
                                                     unsigned* __restrict__ X2,
                                                     int nNodes, int E) {
    int wid  = (blockIdx.x * 256 + threadIdx.x) >> 6;
    int lane = threadIdx.x & 63;
    if (wid >= nNodes) return;
    int d = deg[wid];

    unsigned uf = featbf[(long)wid * (D / 2) + lane];   // own row, hoisted

    float ax0 = 0.f, ay0 = 0.f, ax1 = 0.f, ay1 = 0.f;
    float ax2 = 0.f, ay2 = 0.f, ax3 = 0.f, ay3 = 0.f;

    if (d <= CAP) {
        const int4* ep4 = (const int4*)(edata + (long)wid * CAP);   // 16B-aligned (CAP*8=320B)
        int j = 0;
        // main: 8 edges per iter -> 4 edata + 8 feature loads in flight
        for (; j + 8 <= d; j += 8) {
            int4 p0 = ep4[(j >> 1) + 0];
            int4 p1 = ep4[(j >> 1) + 1];
            int4 p2 = ep4[(j >> 1) + 2];
            int4 p3 = ep4[(j >> 1) + 3];
            unsigned u0 = featbf[(long)p0.x * (D / 2) + lane];
            unsigned u1 = featbf[(long)p0.z * (D / 2) + lane];
            unsigned u2 = featbf[(long)p1.x * (D / 2) + lane];
            unsigned u3 = featbf[(long)p1.z * (D / 2) + lane];
            unsigned u4 = featbf[(long)p2.x * (D / 2) + lane];
            unsigned u5 = featbf[(long)p2.z * (D / 2) + lane];
            unsigned u6 = featbf[(long)p3.x * (D / 2) + lane];
            unsigned u7 = featbf[(long)p3.z * (D / 2) + lane];
            float v0 = __int_as_float(p0.y), v1 = __int_as_float(p0.w);
            float v2 = __int_as_float(p1.y), v3 = __int_as_float(p1.w);
            float v4 = __int_as_float(p2.y), v5 = __int_as_float(p2.w);
            float v6 = __int_as_float(p3.y), v7 = __int_as_float(p3.w);
            ax0 += bflo(u0) * v0; ay0 += bfhi(u0) * v0;
            ax1 += bflo(u1) * v1; ay1 += bfhi(u1) * v1;
            ax2 += bflo(u2) * v2; ay2 += bfhi(u2) * v2;
            ax3 += bflo(u3) * v3; ay3 += bfhi(u3) * v3;
            ax0 += bflo(u4) * v4; ay0 += bfhi(u4) * v4;
            ax1 += bflo(u5) * v5; ay1 += bfhi(u5) * v5;
            ax2 += bflo(u6) * v6; ay2 += bfhi(u6) * v6;
            ax3 += bflo(u7) * v7; ay3 += bfhi(u7) * v7;
        }
        // tail: 2 edges per iter (j stays even)
        for (; j + 2 <= d; j += 2) {
            int4 p = ep4[j >> 1];
            unsigned u0 = featbf[(long)p.x * (D / 2) + lane];
            unsigned u1 = featbf[(long)p.z * (D / 2) + lane];
            float v0 = __int_as_float(p.y), v1 = __int_as_float(p.w);
            ax0 += bflo(u0) * v0; ay0 += bfhi(u0) * v0;
            ax1 += bflo(u1) * v1; ay1 += bfhi(u1) * v1;
        }
        if (j < d) {
            int2 p = edata[(long)wid * CAP + j];
            unsigned u = featbf[(long)p.x * (D / 2) + lane];
            float v = __int_as_float(p.y);
            ax0 += bflo(u) * v; ay0 += bfhi(u) * v;
        }
    } else {
        // exact fallback (statistically never taken): scan all edges
        for (int base = 0; base < E; base += 64) {
            int e = base + lane;
            int t = (e < E) ? tgt[e] : -1;
            unsigned long long m = __ballot(t == wid);
            while (m) {
                int b = __ffsll((long long)m) - 1;
                m &= m - 1;
                int   ee = base + b;
                int   nb = nbr[ee];
                float v  = vals[ee];
                unsigned u = featbf[(long)nb * (D / 2) + lane];
                ax0 += bflo(u) * v;
                ay0 += bfhi(u) * v;
            }
        }
    }

    float accx = (ax0 + ax1) + (ax2 + ax3);
    float accy = (ay0 + ay1) + (ay2 + ay3);
    float fx = bflo(uf), fy = bfhi(uf);
    X1[(long)wid * (D / 2) + lane] = packbf(fx + accx, fy + accy);
    X2[(long)wid * (D / 2) + lane] = packbf(fx * accx, fy * accy);
}

// -------- fused dual-GEMM + bias + leaky relu --------
// W staged in LDS (XOR-swizzled); one wave: 32 nodes x all 128 outs.
__global__ __launch_bounds__(256) void gemm_kernel(const short* __restrict__ X1s,
                                                   const short* __restrict__ X2s,
                                                   const short* __restrict__ Wbf,
                                                   const float* __restrict__ b1,
                                                   const float* __restrict__ b2,
                                                   float* __restrict__ out, int nNodes) {
    __shared__ __align__(16) short sW[2 * D * D];   // 64 KB

    int tid = threadIdx.x;
    // stage W: 4096 16-B chunks, XOR-swizzle chunk pos within row by row&15
    for (int c = tid; c < 4096; c += 256) {
        int r  = c >> 4;          // global row 0..255 (mat*128+row)
        int cc = c & 15;          // chunk within row
        int pp = cc ^ (r & 15);
        *(short8*)(&sW[r * D + pp * 8]) = *(const short8*)(Wbf + c * 8);
    }
    __syncthreads();

    int lane = tid & 63;
    int wid  = (blockIdx.x * 256 + tid) >> 6;
    int m0   = wid * 32;
    if (m0 >= nNodes) return;
    bool t2 = (m0 + 16) < nNodes;   // tiles are all-or-nothing (N % 16 == 0)

    int mrow = lane & 15;   // A: m index / B: n index / D: col index
    int quad = lane >> 4;   // A/B: k-group / D: row-group

    const short* xa1 = X1s + (long)(m0 + mrow) * D + quad * 8;        // tile 0
    const short* xa2 = X2s + (long)(m0 + mrow) * D + quad * 8;
    const short* xb1 = xa1 + 16 * D;                                  // tile 1
    const short* xb2 = xa2 + 16 * D;

    v4f acc[2][8];
#pragma unroll
    for (int t = 0; t < 2; t++)
#pragma unroll
        for (int i = 0; i < 8; i++) acc[t][i] = (v4f)(0.0f);

#pragma unroll
    for (int s = 0; s < 4; s++) {
        short8 a1 = *(const short8*)(xa1 + s * 32);
        short8 a2 = *(const short8*)(xa2 + s * 32);
        short8 c1, c2;
        if (t2) {
            c1 = *(const short8*)(xb1 + s * 32);
            c2 = *(const short8*)(xb2 + s * 32);
        }
        int pp = (s * 4 + quad) ^ mrow;   // swizzled chunk
#pragma unroll
        for (int ot = 0; ot < 8; ot++) {
            int row = ot * 16 + mrow;
            short8 w1 = *(const short8*)(&sW[row * D + pp * 8]);
            short8 w2 = *(const short8*)(&sW[D * D + row * D + pp * 8]);
            acc[0][ot] = __builtin_amdgcn_mfma_f32_16x16x32_bf16(a1, w1, acc[0][ot], 0, 0, 0);
            acc[0][ot] = __builtin_amdgcn_mfma_f32_16x16x32_bf16(a2, w2, acc[0][ot], 0, 0, 0);
            if (t2) {
                acc[1][ot] = __builtin_amdgcn_mfma_f32_16x16x32_bf16(c1, w1, acc[1][ot], 0, 0, 0);
                acc[1][ot] = __builtin_amdgcn_mfma_f32_16x16x32_bf16(c2, w2, acc[1][ot], 0, 0, 0);
            }
        }
    }

#pragma unroll
    for (int ot = 0; ot < 8; ot++) {
        int   o    = ot * 16 + mrow;
        float bias = b1[o] + b2[o];
#pragma unroll
        for (int r = 0; r < 4; r++) {
            int   node = m0 + quad * 4 + r;
            float v    = acc[0][ot][r] + bias;
            out[(long)node * D + o] = (v >= 0.0f) ? v : NEG_SLOPE * v;
            if (t2) {
                float w = acc[1][ot][r] + bias;
                out[(long)(node + 16) * D + o] = (w >= 0.0f) ? w : NEG_SLOPE * w;
            }
        }
    }
}

extern "C" void kernel_launch(void* const* d_in, const int* in_sizes, int n_in,
                              void* d_out, int out_size, void* d_ws, size_t ws_size,
                              hipStream_t stream) {
    const float* feat = (const float*)d_in[0];
    const int*   tgt  = (const int*)d_in[1];
    const int*   nbr  = (const int*)d_in[2];
    const float* vals = (const float*)d_in[3];
    const float* W1   = (const float*)d_in[4];
    const float* b1   = (const float*)d_in[5];
    const float* W2   = (const float*)d_in[6];
    const float* b2   = (const float*)d_in[7];
    float*       out  = (float*)d_out;

    int E      = in_sizes[1];
    int nNodes = out_size / D;

    // ---- workspace layout ----
    int*      deg    = (int*)d_ws;                              // N (even)
    int2*     edata  = (int2*)(deg + nNodes);                   // N*CAP (16B-aligned rows)
    short*    Wbf    = (short*)(edata + (long)nNodes * CAP);    // 2*D*D
    unsigned* featbf = (unsigned*)(Wbf + 2 * D * D);            // N*D/2
    unsigned* X1     = featbf + (long)nNodes * (D / 2);         // N*D/2
    unsigned* X2     = X1 + (long)nNodes * (D / 2);             // N*D/2

    int nPairs = nNodes * (D / 2);

    conv_kernel<<<(nPairs + 255) / 256, 256, 0, stream>>>(feat, W1, W2, featbf, Wbf, deg, nPairs, nNodes);
    bucket_kernel<<<(E + 255) / 256, 256, 0, stream>>>(tgt, nbr, vals, deg, edata, E);
    gather_kernel<<<(nNodes * 64 + 255) / 256, 256, 0, stream>>>(featbf, edata, deg, tgt, nbr, vals,
                                                                 X1, X2, nNodes, E);

    int nPairTiles = (nNodes + 31) / 32;
    int nBlocks    = (nPairTiles + 3) / 4;
    gemm_kernel<<<nBlocks, 256, 0, stream>>>((const short*)X1, (const short*)X2, Wbf, b1, b2, out, nNodes);
}